// Round 4
// baseline (11836.540 us; speedup 1.0000x reference)
//
#include <hip/hip_runtime.h>

typedef _Float16 f16x8 __attribute__((ext_vector_type(8)));
typedef _Float16 f16x4 __attribute__((ext_vector_type(4)));
typedef float f32x4 __attribute__((ext_vector_type(4)));
typedef unsigned long long u64_t;

union FP16U { _Float16 h; unsigned short u; };

__device__ __forceinline__ float sigmoidf_(float x) {
    return __builtin_amdgcn_rcpf(1.f + __expf(-x));
}

__device__ __forceinline__ float tanhf_(float x) {
    float a = fabsf(x);
    float e = __expf(-2.f * a);
    float r = (1.f - e) * __builtin_amdgcn_rcpf(1.f + e);
    return copysignf(r, x);
}

__device__ __forceinline__ f32x4 mfma16(f16x8 a, f16x8 b, f32x4 c) {
    return __builtin_amdgcn_mfma_f32_16x16x32_f16(a, b, c, 0, 0, 0);
}

// ---------------------------------------------------------------------------
// ws layout (bytes):
//   0        : whhA   61440 f16x8 A-fragments (983040 B)
//              frag fr = (jb*2+kh)*20 + fslot ; element = fr*64 + lane (jb 0..23)
//   983040   : wih2f  2304 f16x8 A-fragments, frag = (Mt*12+kt)*64+lane (36864 B)
//   1048576  : sxp2   64*2048*48 f32 (25165824 B) — plain stores, each elem once
//   26214400 : exch   4 groups * 2 bufs * 3072 u64 tagged h-pairs (196608 B)
// ---------------------------------------------------------------------------
// A-fragment semantics (mfma_f32_16x16x32_f16):
//   lane l: A row = (l&15), k = (l>>4)*8 + i ; B col = (l&15), same k
//   lane l: C row = (l>>4)*4 + i, col = (l&15)
// K layout (416): k<384 -> h[k]; 384..403 -> x[k-384]; 404..415 -> 0 pad.
// kh0 fslots: 0..6 R kt0..6 | 7..13 Z kt0..6 | 14..19 HN kt0..5
// kh1 fslots: 0..5 R kt7..12 | 6..11 Z kt7..12 | 12..17 HN kt6..11 | 18 XN kt12

__global__ void pack_weights(const float* __restrict__ Whh1,
                             const float* __restrict__ Wih1,
                             const float* __restrict__ Wih2,
                             _Float16* __restrict__ wsbase) {
    int tid = blockIdx.x * 256 + threadIdx.x;
    f16x8* whhA  = (f16x8*)wsbase;
    f16x8* wih2f = (f16x8*)(wsbase + 983040);
    if (tid < 61440) {
        int l = tid & 63, fr = tid >> 6;
        int fslot = fr % 20, w = fr / 20;
        int kh = w & 1, jb = w >> 1;      // jb = 16-row j-tile, 0..23
        int tile, kt;  // 0=R 1=Z 2=HN 3=XN 4=pad
        if (kh == 0) {
            if (fslot < 7)       { tile = 0; kt = fslot; }
            else if (fslot < 14) { tile = 1; kt = fslot - 7; }
            else                 { tile = 2; kt = fslot - 14; }
        } else {
            if (fslot < 6)       { tile = 0; kt = 7 + fslot; }
            else if (fslot < 12) { tile = 1; kt = 1 + fslot; }
            else if (fslot < 18) { tile = 2; kt = fslot - 6; }
            else if (fslot == 18){ tile = 3; kt = 12; }
            else                 { tile = 4; kt = 0; }
        }
        int gate = (tile == 0) ? 0 : (tile == 1) ? 1 : 2;
        int row = gate * 384 + jb * 16 + (l & 15);
        int k0 = kt * 32 + (l >> 4) * 8;
        f16x8 v;
#pragma unroll
        for (int i = 0; i < 8; ++i) {
            float f = 0.f;
            if (tile != 4) {
                int k = k0 + i;
                if (tile == 3) {
                    int kx = k - 384;
                    f = (kx < 20) ? Wih1[row * 20 + kx] : 0.f;
                } else if (k < 384) {
                    f = Whh1[row * 384 + k];
                } else if (tile < 2) {
                    int kx = k - 384;
                    f = (kx < 20) ? Wih1[row * 20 + kx] : 0.f;
                }
            }
            v[i] = (_Float16)f;
        }
        whhA[tid] = v;
    } else if (tid < 63744) {
        int t2 = tid - 61440;
        int l = t2 & 63, fi = t2 >> 6;   // fi = Mt*12 + kt
        int Mt = fi / 12, kt = fi % 12;
        int row = Mt * 16 + (l & 15);
        int k0 = kt * 32 + (l >> 4) * 8;
        f16x8 v;
#pragma unroll
        for (int i = 0; i < 8; ++i) v[i] = (_Float16)Wih2[row * 384 + k0 + i];
        wih2f[t2] = v;
    }
}

// ---------------------------------------------------------------------------
// gru1_scan v4: 32 blocks = 4 groups (16 batches) x 8 j-chunks (48 j each).
// 6 waves: (jc 0..2) x (kh 0..1 K-split). Whh1 slices register-resident as
// MFMA A-fragments. hhist = 4-deep LDS ring, batch stride 456 halves
// (228 words = 4 mod 32 -> b128 B-fragment reads are bank-conflict-free).
// Exchange: tagged u64 MALL atomics (2 fp16 + tag); kh1 polls 14 words/lane
// (load-all then per-word spin -> one MALL RT). xp2 = 12 full-K single-wave
// MFMA tasks spread over the 8 blocks every 4 steps; plain coalesced stores,
// no atomics, no extra barrier (ordering via S1-of-next-step).
// ---------------------------------------------------------------------------
__global__ __launch_bounds__(384, 1) void gru1_scan(
    const float* __restrict__ x, const float* __restrict__ h1_0,
    const float* __restrict__ bih1, const float* __restrict__ bhh1,
    const f16x8* __restrict__ whhA, const f16x8* __restrict__ wih2f,
    float* __restrict__ sxp2g, u64_t* __restrict__ exch,
    float* __restrict__ h1f_o) {
    const int bid = blockIdx.x;
    const int g = bid >> 3, p = bid & 7;
    const int tid = threadIdx.x;
    const int v = tid >> 6, l = tid & 63;
    const int jc = v >> 1, kh = v & 1;
    const int rg = l >> 4, b = l & 15;
    const int jb = p * 3 + jc;           // global 16-row j-tile (0..23)
    const int j0 = jb * 16 + rg * 4;     // global j base (kh0 lanes)

    __shared__ __align__(16) _Float16 hhist[4][7296];  // [slot][b*456 + k]
    __shared__ __align__(16) float part[3264];         // (jc*64+l)*17 + 16

    // ---- Whh1/Wih1 A fragments into registers ----
    f16x8 A[20];
    {
        const f16x8* ap = whhA + (size_t)((jb * 2 + kh) * 20) * 64 + l;
#pragma unroll
        for (int c = 0; c < 20; ++c) A[c] = ap[c * 64];
    }

    // ---- xp2 task assignment: tasks 0..11 = (Mt = tsk>>2, tq = tsk&3) ----
    int tsk = -1;
    if (v == 0) tsk = p;
    else if (v == 1 && p < 4) tsk = p + 8;
    const int Mtx = (tsk >= 0) ? (tsk >> 2) : 0;
    const int tqx = (tsk >= 0) ? (tsk & 3) : 0;
    f16x8 Ax[12];
    if (tsk >= 0) {
#pragma unroll
        for (int kt = 0; kt < 12; ++kt)
            Ax[kt] = wih2f[(size_t)(Mtx * 12 + kt) * 64 + l];
    }

    // ---- biases + own h state (kh0 lanes own (j0..j0+3, b)) ----
    float bR[4], bZ[4], bXN[4], bHN[4], hp[4];
    if (kh == 0) {
#pragma unroll
        for (int i = 0; i < 4; ++i) {
            int j = j0 + i;
            bR[i]  = bih1[j] + bhh1[j];
            bZ[i]  = bih1[384 + j] + bhh1[384 + j];
            bXN[i] = bih1[768 + j];
            bHN[i] = bhh1[768 + j];
            hp[i]  = h1_0[(size_t)(g * 16 + b) * 384 + j];
        }
    }

    // ---- poll address tables (kh1): 14 remote words per lane ----
    int wo[14], lo[14];
    const int pl = jc * 64 + l;
    if (kh == 1) {
#pragma unroll
        for (int k = 0; k < 14; ++k) {
            int rw = pl + 192 * k;       // 0..2687 remote enumeration
            int jh_r = rw >> 4, b2 = rw & 15;
            int jh = (jh_r < 24 * p) ? jh_r : jh_r + 24;  // skip own 24 jh
            wo[k] = jh * 16 + b2;
            lo[k] = b2 * 456 + jh * 2;
        }
    }
    const int xb2 = pl / 10, xpair = pl % 10;  // x-staging role (kh1, pl<160)

    // ---- prologue: hhist[0] = h_0 | x_0 | pad ; slots 1..3 = 0 ----
    for (int idx = tid; idx < 29184; idx += 384) {
        int s = idx / 7296, r = idx - s * 7296;
        int bb = r / 456, k = r - bb * 456;
        float val = 0.f;
        if (s == 0) {
            if (k < 384) val = h1_0[(size_t)(g * 16 + bb) * 384 + k];
            else if (k < 404) val = x[(size_t)(g * 16 + bb) * 40960 + (k - 384)];
        }
        hhist[s][bb * 456 + k] = (_Float16)val;
    }
    u64_t* exg = exch + (size_t)g * 6144;
    const float* xb = x + (size_t)(g * 16 + xb2) * 40960;
    __syncthreads();

    for (int t = 0; t < 2048; ++t) {
        const _Float16* hc = hhist[t & 3];
        _Float16* hn = hhist[(t + 1) & 3];
        const unsigned tag = (unsigned)(t + 1);
        u64_t* exw = exg + ((t + 1) & 1) * 3072;

        // x prefetch for t+1 (kh1 staging lanes, 2 values each)
        float xr0 = 0.f, xr1 = 0.f;
        if (kh == 1 && pl < 160 && t + 1 < 2048) {
            float2 xv = *(const float2*)(xb + (t + 1) * 20 + 2 * xpair);
            xr0 = xv.x; xr1 = xv.y;
        }

        // ---- gate MFMAs ----
        f32x4 aR{0.f, 0.f, 0.f, 0.f}, aZ{0.f, 0.f, 0.f, 0.f};
        f32x4 aN{0.f, 0.f, 0.f, 0.f}, aX{0.f, 0.f, 0.f, 0.f};
        if (kh == 0) {
#pragma unroll
            for (int ki = 0; ki < 7; ++ki) {
                f16x8 Bf = *(const f16x8*)(hc + b * 456 + ki * 32 + rg * 8);
                aR = mfma16(A[ki], Bf, aR);
                aZ = mfma16(A[7 + ki], Bf, aZ);
                if (ki < 6) aN = mfma16(A[14 + ki], Bf, aN);
            }
        } else {
#pragma unroll
            for (int ki = 0; ki < 7; ++ki) {
                f16x8 Bf = *(const f16x8*)(hc + b * 456 + (6 + ki) * 32 + rg * 8);
                if (ki > 0) {
                    aR = mfma16(A[ki - 1], Bf, aR);
                    aZ = mfma16(A[5 + ki], Bf, aZ);
                }
                if (ki < 6) aN = mfma16(A[12 + ki], Bf, aN);
                if (ki == 6) aX = mfma16(A[18], Bf, aX);
            }
        }

        // ---- kh1: publish K-partials ----
        if (kh == 1) {
            float* pp = part + (jc * 64 + l) * 17;
#pragma unroll
            for (int i = 0; i < 4; ++i) {
                pp[i] = aR[i]; pp[4 + i] = aZ[i];
                pp[8 + i] = aN[i]; pp[12 + i] = aX[i];
            }
        }
        __syncthreads();  // S1

        if (kh == 0) {
            // ---- reduce + pointwise + publish own h ----
            const float* pp = part + (jc * 64 + l) * 17;
            _Float16 hh[4];
#pragma unroll
            for (int i = 0; i < 4; ++i) {
                float sR = aR[i] + pp[i];
                float sZ = aZ[i] + pp[4 + i];
                float sN = aN[i] + pp[8 + i];
                float sX = aX[i] + pp[12 + i];
                float r = sigmoidf_(sR + bR[i]);
                float z = sigmoidf_(sZ + bZ[i]);
                float n = tanhf_(sX + bXN[i] + r * (sN + bHN[i]));
                float h = n + z * (hp[i] - n);
                hp[i] = h;
                hh[i] = (_Float16)h;
            }
            FP16U u0, u1, u2, u3;
            u0.h = hh[0]; u1.h = hh[1]; u2.h = hh[2]; u3.h = hh[3];
            unsigned w01 = (unsigned)u0.u | ((unsigned)u1.u << 16);
            unsigned w23 = (unsigned)u2.u | ((unsigned)u3.u << 16);
            u64_t e0 = (u64_t)w01 | ((u64_t)tag << 32);
            u64_t e1 = (u64_t)w23 | ((u64_t)tag << 32);
            int wA = (j0 >> 1) * 16 + b;
            __hip_atomic_store(exw + wA, e0, __ATOMIC_RELAXED,
                               __HIP_MEMORY_SCOPE_AGENT);
            __hip_atomic_store(exw + wA + 16, e1, __ATOMIC_RELAXED,
                               __HIP_MEMORY_SCOPE_AGENT);
            f16x4 hq; hq[0] = hh[0]; hq[1] = hh[1]; hq[2] = hh[2]; hq[3] = hh[3];
            *(f16x4*)(hn + b * 456 + j0) = hq;
        } else {
            // ---- stage x_{t+1}; poll remote h into hhist[(t+1)&3] ----
            if (pl < 160 && t + 1 < 2048) {
                FP16U a_, b_;
                a_.h = (_Float16)xr0; b_.h = (_Float16)xr1;
                *(unsigned*)(hn + xb2 * 456 + 384 + 2 * xpair) =
                    (unsigned)a_.u | ((unsigned)b_.u << 16);
            }
            u64_t w[14];
#pragma unroll
            for (int k = 0; k < 14; ++k)
                w[k] = __hip_atomic_load(exw + wo[k], __ATOMIC_RELAXED,
                                         __HIP_MEMORY_SCOPE_AGENT);
#pragma unroll
            for (int k = 0; k < 14; ++k) {
                while ((unsigned)(w[k] >> 32) != tag)
                    w[k] = __hip_atomic_load(exw + wo[k], __ATOMIC_RELAXED,
                                             __HIP_MEMORY_SCOPE_AGENT);
            }
#pragma unroll
            for (int k = 0; k < 14; ++k)
                *(unsigned*)(hn + lo[k]) = (unsigned)w[k];
        }
        __syncthreads();  // S2: hhist[(t+1)&3] = h_{t+1} | x_{t+1} complete

        // ---- xp2 every 4 steps: task wave computes sxp2[b][t-3+tq][Mt*16..]
        // with full K=384 (12 MFMA, no reduce). h_{t'+1} is in slot (1+tq)&3.
        // Race-free: step t+1 writes slot (t+2)&3 only after S1 of t+1; these
        // ds_reads complete before this wave passes that barrier.
        if ((t & 3) == 3 && tsk >= 0) {
            const _Float16* hx = hhist[(1 + tqx) & 3];
            f32x4 acc{0.f, 0.f, 0.f, 0.f};
#pragma unroll
            for (int kt = 0; kt < 12; ++kt) {
                f16x8 Bf = *(const f16x8*)(hx + b * 456 + kt * 32 + rg * 8);
                acc = mfma16(Ax[kt], Bf, acc);
            }
            *(float4*)(sxp2g +
                ((size_t)(g * 16 + b) * 2048 + (t - 3 + tqx)) * 48 +
                Mtx * 16 + rg * 4) =
                make_float4(acc[0], acc[1], acc[2], acc[3]);
        }
    }

    if (kh == 0) {
        float4 hv = make_float4(hp[0], hp[1], hp[2], hp[3]);
        *(float4*)(h1f_o + (size_t)(g * 16 + b) * 384 + j0) = hv;
    }
}

// ---------------------------------------------------------------------------
// Tail: GRU2+ReLU+FC forward (from sxp2), then GRU3 reverse. One wave per
// batch; recurrent state replicated per-lane, re-broadcast via one LDS write
// + broadcast reads (3 shfl/step instead of 35-43).
// ---------------------------------------------------------------------------
__global__ __launch_bounds__(64) void tail_scan(
    const float* __restrict__ sxp2g, const float* __restrict__ h2_0,
    const float* __restrict__ h3_0,
    const float* __restrict__ Whh2, const float* __restrict__ bih2,
    const float* __restrict__ bhh2,
    const float* __restrict__ Wfc, const float* __restrict__ bfc,
    const float* __restrict__ Wih3, const float* __restrict__ Whh3,
    const float* __restrict__ bih3, const float* __restrict__ bhh3,
    float* __restrict__ xmid, float* __restrict__ xout,
    float* __restrict__ h2f_o, float* __restrict__ h3f_o) {
    const int b = blockIdx.x;
    const int l = threadIdx.x;

    __shared__ __align__(16) float hs[32];  // state broadcast staging

    // ================= loop 1: GRU2 + ReLU + FC + 2*tanh =================
    float w2r[16]; float bx2 = 0.f, bh2 = 0.f;
    if (l < 48) {
#pragma unroll
        for (int k = 0; k < 16; ++k) w2r[k] = Whh2[l * 16 + k];
        bx2 = bih2[l]; bh2 = bhh2[l];
    }
    float wfc[16]; float bf = 0.f;
    if (l < 20) {
#pragma unroll
        for (int k = 0; k < 16; ++k) wfc[k] = Wfc[l * 16 + k];
        bf = bfc[l];
    }
    float h2all[16];
    {
        const float4* hp = (const float4*)(h2_0 + b * 16);
#pragma unroll
        for (int c = 0; c < 4; ++c) {
            float4 v = hp[c];
            h2all[c * 4 + 0] = v.x; h2all[c * 4 + 1] = v.y;
            h2all[c * 4 + 2] = v.z; h2all[c * 4 + 3] = v.w;
        }
    }
    float hown = (l < 16) ? h2_0[b * 16 + l] : 0.f;

    float* xm = xmid + (size_t)b * 40960;
    const float* sx = sxp2g + (size_t)b * 98304;

    float pre[8];
#pragma unroll
    for (int i = 0; i < 8; ++i) pre[i] = (l < 48) ? sx[i * 48 + l] : 0.f;

    for (int tg = 0; tg < 256; ++tg) {
#pragma unroll
        for (int tq = 0; tq < 8; ++tq) {
            const int t = tg * 8 + tq;
            float ax = pre[tq] + bx2;
            if (l < 48 && t + 8 < 2048) pre[tq] = sx[(size_t)(t + 8) * 48 + l];
            float a0 = 0.f, a1 = 0.f;
#pragma unroll
            for (int k = 0; k < 8; ++k) {
                a0 = __builtin_fmaf(h2all[k], w2r[k], a0);
                a1 = __builtin_fmaf(h2all[8 + k], w2r[8 + k], a1);
            }
            float ah = bh2 + a0 + a1;
            float s_   = ax + ah;
            float zpre = __shfl(s_, (16 + l) & 63);
            float xn3  = __shfl(ax, (32 + l) & 63);
            float ghn  = __shfl(ah, (32 + l) & 63);
            float r2 = sigmoidf_(s_);
            float z2 = sigmoidf_(zpre);
            float n2 = tanhf_(xn3 + r2 * ghn);
            float h2n = (1.f - z2) * n2 + z2 * hown;
            if (l < 16) { hown = h2n; hs[l] = h2n; }
            __builtin_amdgcn_wave_barrier();
            {
                const float4* hv = (const float4*)hs;
#pragma unroll
                for (int c = 0; c < 4; ++c) {
                    float4 v = hv[c];
                    h2all[c * 4 + 0] = v.x; h2all[c * 4 + 1] = v.y;
                    h2all[c * 4 + 2] = v.z; h2all[c * 4 + 3] = v.w;
                }
            }
            float f0 = 0.f, f1 = 0.f;
#pragma unroll
            for (int k = 0; k < 8; ++k) {
                f0 = __builtin_fmaf(fmaxf(h2all[k], 0.f), wfc[k], f0);
                f1 = __builtin_fmaf(fmaxf(h2all[8 + k], 0.f), wfc[8 + k], f1);
            }
            float a = bf + f0 + f1;
            if (l < 20) xm[t * 20 + l] = 2.f * tanhf_(a);
        }
    }
    if (l < 16) h2f_o[b * 16 + l] = hown;

    // ================= loop 2: GRU3 over reversed xmid =================
    float wi3[20], wh3[20]; float bx3 = 0.f, bh3 = 0.f;
    if (l < 60) {
#pragma unroll
        for (int k = 0; k < 20; ++k) {
            wi3[k] = Wih3[l * 20 + k];
            wh3[k] = Whh3[l * 20 + k];
        }
        bx3 = bih3[l]; bh3 = bhh3[l];
    }
    float h3all[20];
    {
        const float4* hp = (const float4*)(h3_0 + b * 20);
#pragma unroll
        for (int c = 0; c < 5; ++c) {
            float4 v = hp[c];
            h3all[c * 4 + 0] = v.x; h3all[c * 4 + 1] = v.y;
            h3all[c * 4 + 2] = v.z; h3all[c * 4 + 3] = v.w;
        }
    }
    float h3own = (l < 20) ? h3_0[b * 20 + l] : 0.f;
    float* xo = xout + (size_t)b * 40960;

    float4 px[4][5];
#pragma unroll
    for (int i = 0; i < 4; ++i) {
        const float4* xr = (const float4*)(xm + (size_t)(2047 - i) * 20);
#pragma unroll
        for (int c = 0; c < 5; ++c) px[i][c] = xr[c];
    }

    for (int tg = 0; tg < 512; ++tg) {
#pragma unroll
        for (int tq = 0; tq < 4; ++tq) {
            const int t = 2047 - (tg * 4 + tq);
            float xv[20];
#pragma unroll
            for (int c = 0; c < 5; ++c) {
                float4 v = px[tq][c];
                xv[c * 4 + 0] = v.x; xv[c * 4 + 1] = v.y;
                xv[c * 4 + 2] = v.z; xv[c * 4 + 3] = v.w;
            }
            if (t - 4 >= 0) {
                const float4* xr = (const float4*)(xm + (size_t)(t - 4) * 20);
#pragma unroll
                for (int c = 0; c < 5; ++c) px[tq][c] = xr[c];
            }
            float x0 = 0.f, x1 = 0.f, g0 = 0.f, g1 = 0.f;
#pragma unroll
            for (int k = 0; k < 10; ++k) {
                x0 = __builtin_fmaf(xv[k], wi3[k], x0);
                x1 = __builtin_fmaf(xv[10 + k], wi3[10 + k], x1);
                g0 = __builtin_fmaf(h3all[k], wh3[k], g0);
                g1 = __builtin_fmaf(h3all[10 + k], wh3[10 + k], g1);
            }
            float ax = bx3 + x0 + x1;
            float ah = bh3 + g0 + g1;
            float s_   = ax + ah;
            float zpre = __shfl(s_, (20 + l) & 63);
            float xn_  = __shfl(ax, (40 + l) & 63);
            float ghn  = __shfl(ah, (40 + l) & 63);
            float r = sigmoidf_(s_);
            float z = sigmoidf_(zpre);
            float n = tanhf_(xn_ + r * ghn);
            float hn = (1.f - z) * n + z * h3own;
            if (l < 20) {
                h3own = hn;
                hs[l] = hn;
                xo[(size_t)(2047 - t) * 20 + l] = tanhf_(hn);
            }
            __builtin_amdgcn_wave_barrier();
#pragma unroll
            for (int c = 0; c < 5; ++c) {
                float4 v = ((const float4*)hs)[c];
                h3all[c * 4 + 0] = v.x; h3all[c * 4 + 1] = v.y;
                h3all[c * 4 + 2] = v.z; h3all[c * 4 + 3] = v.w;
            }
        }
    }
    if (l < 20) h3f_o[b * 20 + l] = h3own;
}

extern "C" void kernel_launch(void* const* d_in, const int* in_sizes, int n_in,
                              void* d_out, int out_size, void* d_ws, size_t ws_size,
                              hipStream_t stream) {
    const float* x    = (const float*)d_in[0];
    const float* h1   = (const float*)d_in[1];
    const float* h2   = (const float*)d_in[2];
    const float* h3   = (const float*)d_in[3];
    const float* Wih1 = (const float*)d_in[4];
    const float* Whh1 = (const float*)d_in[5];
    const float* bih1 = (const float*)d_in[6];
    const float* bhh1 = (const float*)d_in[7];
    const float* Wih2 = (const float*)d_in[8];
    const float* Whh2 = (const float*)d_in[9];
    const float* bih2 = (const float*)d_in[10];
    const float* bhh2 = (const float*)d_in[11];
    const float* Wih3 = (const float*)d_in[12];
    const float* Whh3 = (const float*)d_in[13];
    const float* bih3 = (const float*)d_in[14];
    const float* bhh3 = (const float*)d_in[15];
    const float* Wfc  = (const float*)d_in[16];
    const float* bfc  = (const float*)d_in[17];

    float* out  = (float*)d_out;
    float* xmid = out;                  // (64,2048,20)
    float* xout = out + 2621440;        // (64,2048,20)
    float* h1f  = out + 5242880;        // (64,384)
    float* h2f  = out + 5267456;        // (64,16)
    float* h3f  = out + 5268480;        // (64,20)

    char* ws = (char*)d_ws;
    _Float16* wsh  = (_Float16*)ws;
    float*    sxp2 = (float*)(ws + 1048576);
    u64_t*    exch = (u64_t*)(ws + 26214400);

    hipMemsetAsync(exch, 0, 196608, stream);  // tags := 0 (never matches 1..2048)
    pack_weights<<<249, 256, 0, stream>>>(Whh1, Wih1, Wih2, wsh);
    gru1_scan<<<32, 384, 0, stream>>>(x, h1, bih1, bhh1,
                                      (const f16x8*)wsh,
                                      (const f16x8*)(wsh + 983040),
                                      sxp2, exch, h1f);
    tail_scan<<<64, 64, 0, stream>>>(sxp2, h2, h3,
                                     Whh2, bih2, bhh2, Wfc, bfc,
                                     Wih3, Whh3, bih3, bhh3,
                                     xmid, xout, h2f, h3f);
}

// Round 5
// 4996.761 us; speedup vs baseline: 2.3688x; 2.3688x over previous
//
#include <hip/hip_runtime.h>

typedef _Float16 f16x8 __attribute__((ext_vector_type(8)));
typedef _Float16 f16x2 __attribute__((ext_vector_type(2)));

union F16x8U { f16x8 v8; f16x2 v2[4]; };
union FP16U { _Float16 h; unsigned short u; };

__device__ __forceinline__ float dot2acc(f16x2 a, f16x2 b, float c) {
#if __has_builtin(__builtin_amdgcn_fdot2)
    return __builtin_amdgcn_fdot2(a, b, c, false);
#else
    return c + (float)a[0] * (float)b[0] + (float)a[1] * (float)b[1];
#endif
}

__device__ __forceinline__ float sigmoidf_(float x) {
    return __builtin_amdgcn_rcpf(1.f + __expf(-x));
}

__device__ __forceinline__ float tanhf_(float x) {
    float a = fabsf(x);
    float e = __expf(-2.f * a);
    float r = (1.f - e) * __builtin_amdgcn_rcpf(1.f + e);
    return copysignf(r, x);
}

// ---------------------------------------------------------------------------
// ws layout (bytes):
//   0         : whhp  55296 f16x8 chunks (884736 B) — per-thread reg layout
//   884736    : wih1p 3456 f16x8 chunks (55296 B)
//   940032    : wih2h 18432 fp16 (36864 B)
//   1048576   : sxp2  (64*2048*48 f32, 25.17 MB)
//   26214400  : exch  (2 buffers * 64*384 u32 tagged fp16, 196608 B)
// ---------------------------------------------------------------------------

// whhp chunk idx = ((q*8+ko)*96 + jl)*18 + g*6 + m : Whh1[g*384+q*96+jl][ko*48+m*8 ..+7]
// wih1p chunk idx = ((q*3+g)*96 + jl)*3 + m        : Wih1[g*384+q*96+jl][m*8 ..+7] (K pad 24)
__global__ void pack_weights(const float* __restrict__ Whh1,
                             const float* __restrict__ Wih1,
                             const float* __restrict__ Wih2,
                             _Float16* __restrict__ wsbase) {
    int tid = blockIdx.x * 256 + threadIdx.x;
    f16x8* whhp  = (f16x8*)wsbase;
    f16x8* wih1p = (f16x8*)(wsbase + 442368);
    _Float16* wih2h = wsbase + 470016;
    if (tid < 55296) {
        int c = tid % 18, thr = tid / 18;
        int g = c / 6, m = c % 6;
        int jl = thr % 96, ko = (thr / 96) % 8, q = thr / 768;
        int row = g * 384 + q * 96 + jl;
        int kb = ko * 48 + m * 8;
        f16x8 v;
#pragma unroll
        for (int i = 0; i < 8; ++i) v[i] = (_Float16)Whh1[row * 384 + kb + i];
        whhp[tid] = v;
    } else if (tid < 58752) {
        int t2 = tid - 55296;
        int m = t2 % 3, thr = t2 / 3;
        int jl = thr % 96, g = (thr / 96) % 3, q = thr / 288;
        int row = g * 384 + q * 96 + jl;
        f16x8 v;
#pragma unroll
        for (int i = 0; i < 8; ++i) {
            int kk = m * 8 + i;
            v[i] = (kk < 20) ? (_Float16)Wih1[row * 20 + kk] : (_Float16)0.f;
        }
        wih1p[t2] = v;
    } else if (tid < 77184) {
        int t3 = tid - 58752;
        wih2h[t3] = (_Float16)Wih2[t3];
    }
}

// ---------------------------------------------------------------------------
// gru1_scan v5: 256 blocks, 4 per batch (q = j-quarter), v1's proven layout
// (weights in registers, tagged u32 MALL exchange) with the step RESTRUCTURED
// so the MALL round-trip is overlapped with dot compute.
//
// A thread's k-window (ko*48..+47) lies entirely in quarter (ko>>1). Phases:
//   A: owners (tid<96) reduce part4 + pointwise -> h_{t+1}; publish to exch
//      (tagged), h1h local slice, hhist. Stagers (tid 96..115) write x_{t+1}
//      to xsh and prefetch x_{t+2}.                                [B1]
//   B: LOCAL-K waves (ko>>1 == q, 3 waves, 192-aligned) compute their dots
//      for step t+1 (h1h local slice just written) WHILE pollers (288 remote
//      threads) wait out the store->MALL->load RT for remote h.    [B2]
//   C: REMOTE-K waves (9) compute their dots for step t+1; xp2 every 4
//      steps (unchanged v1 code).                                  [B3]
// Serial path/step: pointwise + RT + remote-dots  (v1: all-dots + pointwise
// + RT). Hazards: part4 written B/C, read next A (B3 between); h1h local
// written A, read B (B1); h1h remote written B, read C (B2); xsh written A,
// read B/C (B1); hhist written A/B, read C-xp2 (B2).
// ---------------------------------------------------------------------------
__global__ __launch_bounds__(768, 3) void gru1_scan(
    const float* __restrict__ x, const float* __restrict__ h1_0,
    const float* __restrict__ bih1, const float* __restrict__ bhh1,
    const f16x8* __restrict__ whhp, const f16x8* __restrict__ wih1p,
    const _Float16* __restrict__ wih2h,
    float* __restrict__ sxp2g, unsigned* __restrict__ exch,
    float* __restrict__ h1f_o) {
    const int bid = blockIdx.x;
    const int b = bid >> 2, q = bid & 3;
    const int tid = threadIdx.x;
    const int ko = tid / 96, jl = tid % 96;
    const int lq = ko >> 1;                 // k-quarter this thread's dots need

    __shared__ __align__(16) _Float16 h1h[384];
    __shared__ __align__(16) _Float16 hhist[4][384];
    __shared__ __align__(16) _Float16 xsh[2][24];
    __shared__ __align__(16) float4 part4[8 * 96];
    __shared__ float part2[4 * 12 * 65];

    // ---- weights into registers ----
    F16x8U W[18];
    {
        const f16x8* wp = whhp + ((size_t)((q * 8 + ko) * 96 + jl)) * 18;
#pragma unroll
        for (int c = 0; c < 18; ++c) W[c].v8 = wp[c];
    }
    F16x8U Wx[3];
    if (ko < 3) {
        const f16x8* wp = wih1p + ((size_t)((q * 3 + ko) * 96 + jl)) * 3;
#pragma unroll
        for (int c = 0; c < 3; ++c) Wx[c].v8 = wp[c];
    }

    float cbr = 0.f, cbz = 0.f, cxn = 0.f, chn = 0.f, hprev = 0.f;
    if (tid < 96) {
        int j = q * 96 + tid;
        cbr = bih1[j] + bhh1[j];
        cbz = bih1[384 + j] + bhh1[384 + j];
        cxn = bih1[768 + j];
        chn = bhh1[768 + j];
        hprev = h1_0[b * 384 + j];
    }
    if (tid < 384) h1h[tid] = (_Float16)h1_0[b * 384 + tid];
    const float* xb = x + (size_t)b * 40960;
    if (tid < 24) {
        xsh[0][tid] = (_Float16)((tid < 20) ? xb[tid] : 0.f);
        xsh[1][tid] = (_Float16)0.f;
    }
    // stager x prefetch register: holds x_{t+1} at iteration t entry
    float xreg = 0.f;
    if (tid >= 96 && tid < 116) xreg = xb[20 + (tid - 96)];

    unsigned* exb0 = exch + (size_t)b * 384;
    unsigned* exb1 = exch + 24576 + (size_t)b * 384;

    // remote-thread enumeration (valid when lq != q): rt in [0,576)
    const int rt = (tid < 192 * q) ? tid : tid - 192;
    const bool isloc = (lq == q);
    const int gslot = (!isloc && rt < 288) ? ((q * 96 + 96 + rt) % 384) : 0;

    const int o2 = tid >> 6, ks = tid & 63;
    const _Float16* w2row = wih2h + (q * 12 + o2) * 384 + ks * 6;

    // per-thread partial gate dots (k-window ko*48..+47) for step t+1;
    // xpar selects the xsh buffer holding x_{t+1}.
    auto gate_dots = [&](int xpar) {
        float ar = 0.f, az = 0.f, ahn = 0.f, axn = 0.f;
        const _Float16* hbase = h1h + ko * 48;
#pragma unroll
        for (int m = 0; m < 6; ++m) {
            F16x8U hv; hv.v8 = *(const f16x8*)(hbase + m * 8);
#pragma unroll
            for (int i = 0; i < 4; ++i) {
                ar  = dot2acc(W[m].v2[i],      hv.v2[i], ar);
                az  = dot2acc(W[6 + m].v2[i],  hv.v2[i], az);
                ahn = dot2acc(W[12 + m].v2[i], hv.v2[i], ahn);
            }
        }
        if (ko < 3) {
            float acc = 0.f;
            const _Float16* xs = xsh[xpar];
#pragma unroll
            for (int m = 0; m < 3; ++m) {
                F16x8U xv; xv.v8 = *(const f16x8*)(xs + m * 8);
#pragma unroll
                for (int i = 0; i < 4; ++i)
                    acc = dot2acc(Wx[m].v2[i], xv.v2[i], acc);
            }
            if (ko == 0) ar += acc;
            else if (ko == 1) az += acc;
            else axn += acc;
        }
        part4[ko * 96 + jl] = make_float4(ar, az, ahn, axn);
    };

    __syncthreads();
    gate_dots(0);          // dots for step 0 (h_0, x_0)
    __syncthreads();

    for (int t = 0; t < 2048; ++t) {
        const unsigned tag = (unsigned)(t + 1);
        unsigned* exw = ((t + 1) & 1) ? exb1 : exb0;

        // ---- phase A: owners finalize h_{t+1}; stagers refresh xsh ----
        if (tid < 96) {
            float sr = cbr, sz = cbz, snh = chn, snx = cxn;
#pragma unroll
            for (int k = 0; k < 8; ++k) {
                float4 p = part4[k * 96 + tid];
                sr += p.x; sz += p.y; snh += p.z; snx += p.w;
            }
            float r = sigmoidf_(sr), z = sigmoidf_(sz);
            float n = tanhf_(snx + r * snh);
            hprev = (1.f - z) * n + z * hprev;
            FP16U hu; hu.h = (_Float16)hprev;
            __hip_atomic_store(&exw[q * 96 + tid], (tag << 16) | (unsigned)hu.u,
                               __ATOMIC_RELAXED, __HIP_MEMORY_SCOPE_AGENT);
            h1h[q * 96 + tid] = hu.h;
            hhist[t & 3][q * 96 + tid] = hu.h;
        } else if (tid < 116) {
            xsh[(t + 1) & 1][tid - 96] = (_Float16)xreg;     // x_{t+1}
            if (t + 2 < 2048) xreg = xb[(t + 2) * 20 + (tid - 96)];
        }
        __syncthreads();  // B1

        // ---- phase B: local-K dots overlap the remote-h MALL round-trip ----
        if (isloc) {
            gate_dots((t + 1) & 1);
        } else if (rt < 288) {
            unsigned w;
            do {
                w = __hip_atomic_load(&exw[gslot], __ATOMIC_RELAXED,
                                      __HIP_MEMORY_SCOPE_AGENT);
            } while ((w >> 16) != tag);
            FP16U hu; hu.u = (unsigned short)(w & 0xffffu);
            h1h[gslot] = hu.h;
            hhist[t & 3][gslot] = hu.h;
        }
        __syncthreads();  // B2: h_{t+1} complete in h1h

        // ---- phase C: remote-K dots; xp2 every 4 steps ----
        if (!isloc) gate_dots((t + 1) & 1);

        if ((t & 3) == 3) {
            f16x2 w0 = *(const f16x2*)(w2row);
            f16x2 w1 = *(const f16x2*)(w2row + 2);
            f16x2 w2 = *(const f16x2*)(w2row + 4);
#pragma unroll
            for (int tq = 0; tq < 4; ++tq) {
                const _Float16* hrow = hhist[tq] + ks * 6;
                float a = dot2acc(w0, *(const f16x2*)hrow, 0.f);
                a = dot2acc(w1, *(const f16x2*)(hrow + 2), a);
                a = dot2acc(w2, *(const f16x2*)(hrow + 4), a);
                part2[(tq * 12 + o2) * 65 + ks] = a;
            }
            __syncthreads();  // S3
            if (tid < 48) {
                int tq = tid / 12, o = tid % 12;
                const float* pr = &part2[(tq * 12 + o) * 65];
                float s0 = 0.f, s1 = 0.f, s2 = 0.f, s3 = 0.f;
#pragma unroll
                for (int i2 = 0; i2 < 16; ++i2) {
                    s0 += pr[i2 * 4];     s1 += pr[i2 * 4 + 1];
                    s2 += pr[i2 * 4 + 2]; s3 += pr[i2 * 4 + 3];
                }
                sxp2g[((size_t)b * 2048 + (t - 3 + tq)) * 48 + q * 12 + o] =
                    (s0 + s1) + (s2 + s3);
            }
        }
        __syncthreads();  // B3: part4 complete for next phase A
    }
    if (tid < 96) h1f_o[b * 384 + q * 96 + tid] = hprev;
}

// ---------------------------------------------------------------------------
// Tail: GRU2+ReLU+FC forward (from sxp2), then GRU3 reverse. One wave per
// batch; recurrent state replicated per-lane, re-broadcast via one LDS write
// + broadcast reads (3 shfl/step instead of 35-43). Proven 1.16 ms (r1).
// ---------------------------------------------------------------------------
__global__ __launch_bounds__(64) void tail_scan(
    const float* __restrict__ sxp2g, const float* __restrict__ h2_0,
    const float* __restrict__ h3_0,
    const float* __restrict__ Whh2, const float* __restrict__ bih2,
    const float* __restrict__ bhh2,
    const float* __restrict__ Wfc, const float* __restrict__ bfc,
    const float* __restrict__ Wih3, const float* __restrict__ Whh3,
    const float* __restrict__ bih3, const float* __restrict__ bhh3,
    float* __restrict__ xmid, float* __restrict__ xout,
    float* __restrict__ h2f_o, float* __restrict__ h3f_o) {
    const int b = blockIdx.x;
    const int l = threadIdx.x;

    __shared__ __align__(16) float hs[32];  // state broadcast staging

    // ================= loop 1: GRU2 + ReLU + FC + 2*tanh =================
    float w2r[16]; float bx2 = 0.f, bh2 = 0.f;
    if (l < 48) {
#pragma unroll
        for (int k = 0; k < 16; ++k) w2r[k] = Whh2[l * 16 + k];
        bx2 = bih2[l]; bh2 = bhh2[l];
    }
    float wfc[16]; float bf = 0.f;
    if (l < 20) {
#pragma unroll
        for (int k = 0; k < 16; ++k) wfc[k] = Wfc[l * 16 + k];
        bf = bfc[l];
    }
    float h2all[16];
    {
        const float4* hp = (const float4*)(h2_0 + b * 16);
#pragma unroll
        for (int c = 0; c < 4; ++c) {
            float4 v = hp[c];
            h2all[c * 4 + 0] = v.x; h2all[c * 4 + 1] = v.y;
            h2all[c * 4 + 2] = v.z; h2all[c * 4 + 3] = v.w;
        }
    }
    float hown = (l < 16) ? h2_0[b * 16 + l] : 0.f;

    float* xm = xmid + (size_t)b * 40960;
    const float* sx = sxp2g + (size_t)b * 98304;

    float pre[8];
#pragma unroll
    for (int i = 0; i < 8; ++i) pre[i] = (l < 48) ? sx[i * 48 + l] : 0.f;

    for (int tg = 0; tg < 256; ++tg) {
#pragma unroll
        for (int tq = 0; tq < 8; ++tq) {
            const int t = tg * 8 + tq;
            float ax = pre[tq] + bx2;
            if (l < 48 && t + 8 < 2048) pre[tq] = sx[(size_t)(t + 8) * 48 + l];
            float a0 = 0.f, a1 = 0.f;
#pragma unroll
            for (int k = 0; k < 8; ++k) {
                a0 = __builtin_fmaf(h2all[k], w2r[k], a0);
                a1 = __builtin_fmaf(h2all[8 + k], w2r[8 + k], a1);
            }
            float ah = bh2 + a0 + a1;
            float s_   = ax + ah;
            float zpre = __shfl(s_, (16 + l) & 63);
            float xn3  = __shfl(ax, (32 + l) & 63);
            float ghn  = __shfl(ah, (32 + l) & 63);
            float r2 = sigmoidf_(s_);
            float z2 = sigmoidf_(zpre);
            float n2 = tanhf_(xn3 + r2 * ghn);
            float h2n = (1.f - z2) * n2 + z2 * hown;
            if (l < 16) { hown = h2n; hs[l] = h2n; }
            __builtin_amdgcn_wave_barrier();
            {
                const float4* hv = (const float4*)hs;
#pragma unroll
                for (int c = 0; c < 4; ++c) {
                    float4 v = hv[c];
                    h2all[c * 4 + 0] = v.x; h2all[c * 4 + 1] = v.y;
                    h2all[c * 4 + 2] = v.z; h2all[c * 4 + 3] = v.w;
                }
            }
            float f0 = 0.f, f1 = 0.f;
#pragma unroll
            for (int k = 0; k < 8; ++k) {
                f0 = __builtin_fmaf(fmaxf(h2all[k], 0.f), wfc[k], f0);
                f1 = __builtin_fmaf(fmaxf(h2all[8 + k], 0.f), wfc[8 + k], f1);
            }
            float a = bf + f0 + f1;
            if (l < 20) xm[t * 20 + l] = 2.f * tanhf_(a);
        }
    }
    if (l < 16) h2f_o[b * 16 + l] = hown;

    // ================= loop 2: GRU3 over reversed xmid =================
    float wi3[20], wh3[20]; float bx3 = 0.f, bh3 = 0.f;
    if (l < 60) {
#pragma unroll
        for (int k = 0; k < 20; ++k) {
            wi3[k] = Wih3[l * 20 + k];
            wh3[k] = Whh3[l * 20 + k];
        }
        bx3 = bih3[l]; bh3 = bhh3[l];
    }
    float h3all[20];
    {
        const float4* hp = (const float4*)(h3_0 + b * 20);
#pragma unroll
        for (int c = 0; c < 5; ++c) {
            float4 v = hp[c];
            h3all[c * 4 + 0] = v.x; h3all[c * 4 + 1] = v.y;
            h3all[c * 4 + 2] = v.z; h3all[c * 4 + 3] = v.w;
        }
    }
    float h3own = (l < 20) ? h3_0[b * 20 + l] : 0.f;
    float* xo = xout + (size_t)b * 40960;

    float4 px[4][5];
#pragma unroll
    for (int i = 0; i < 4; ++i) {
        const float4* xr = (const float4*)(xm + (size_t)(2047 - i) * 20);
#pragma unroll
        for (int c = 0; c < 5; ++c) px[i][c] = xr[c];
    }

    for (int tg = 0; tg < 512; ++tg) {
#pragma unroll
        for (int tq = 0; tq < 4; ++tq) {
            const int t = 2047 - (tg * 4 + tq);
            float xv[20];
#pragma unroll
            for (int c = 0; c < 5; ++c) {
                float4 v = px[tq][c];
                xv[c * 4 + 0] = v.x; xv[c * 4 + 1] = v.y;
                xv[c * 4 + 2] = v.z; xv[c * 4 + 3] = v.w;
            }
            if (t - 4 >= 0) {
                const float4* xr = (const float4*)(xm + (size_t)(t - 4) * 20);
#pragma unroll
                for (int c = 0; c < 5; ++c) px[tq][c] = xr[c];
            }
            float x0 = 0.f, x1 = 0.f, g0 = 0.f, g1 = 0.f;
#pragma unroll
            for (int k = 0; k < 10; ++k) {
                x0 = __builtin_fmaf(xv[k], wi3[k], x0);
                x1 = __builtin_fmaf(xv[10 + k], wi3[10 + k], x1);
                g0 = __builtin_fmaf(h3all[k], wh3[k], g0);
                g1 = __builtin_fmaf(h3all[10 + k], wh3[10 + k], g1);
            }
            float ax = bx3 + x0 + x1;
            float ah = bh3 + g0 + g1;
            float s_   = ax + ah;
            float zpre = __shfl(s_, (20 + l) & 63);
            float xn_  = __shfl(ax, (40 + l) & 63);
            float ghn  = __shfl(ah, (40 + l) & 63);
            float r = sigmoidf_(s_);
            float z = sigmoidf_(zpre);
            float n = tanhf_(xn_ + r * ghn);
            float hn = (1.f - z) * n + z * h3own;
            if (l < 20) {
                h3own = hn;
                hs[l] = hn;
                xo[(size_t)(2047 - t) * 20 + l] = tanhf_(hn);
            }
            __builtin_amdgcn_wave_barrier();
#pragma unroll
            for (int c = 0; c < 5; ++c) {
                float4 v = ((const float4*)hs)[c];
                h3all[c * 4 + 0] = v.x; h3all[c * 4 + 1] = v.y;
                h3all[c * 4 + 2] = v.z; h3all[c * 4 + 3] = v.w;
            }
        }
    }
    if (l < 20) h3f_o[b * 20 + l] = h3own;
}

extern "C" void kernel_launch(void* const* d_in, const int* in_sizes, int n_in,
                              void* d_out, int out_size, void* d_ws, size_t ws_size,
                              hipStream_t stream) {
    const float* x    = (const float*)d_in[0];
    const float* h1   = (const float*)d_in[1];
    const float* h2   = (const float*)d_in[2];
    const float* h3   = (const float*)d_in[3];
    const float* Wih1 = (const float*)d_in[4];
    const float* Whh1 = (const float*)d_in[5];
    const float* bih1 = (const float*)d_in[6];
    const float* bhh1 = (const float*)d_in[7];
    const float* Wih2 = (const float*)d_in[8];
    const float* Whh2 = (const float*)d_in[9];
    const float* bih2 = (const float*)d_in[10];
    const float* bhh2 = (const float*)d_in[11];
    const float* Wih3 = (const float*)d_in[12];
    const float* Whh3 = (const float*)d_in[13];
    const float* bih3 = (const float*)d_in[14];
    const float* bhh3 = (const float*)d_in[15];
    const float* Wfc  = (const float*)d_in[16];
    const float* bfc  = (const float*)d_in[17];

    float* out  = (float*)d_out;
    float* xmid = out;                  // (64,2048,20)
    float* xout = out + 2621440;        // (64,2048,20)
    float* h1f  = out + 5242880;        // (64,384)
    float* h2f  = out + 5267456;        // (64,16)
    float* h3f  = out + 5268480;        // (64,20)

    char* ws = (char*)d_ws;
    _Float16* wsh  = (_Float16*)ws;
    float*    sxp2 = (float*)(ws + 1048576);
    unsigned* exch = (unsigned*)(ws + 26214400);

    hipMemsetAsync(exch, 0, 196608, stream);  // tags := 0 (never matches 1..2048)
    pack_weights<<<302, 256, 0, stream>>>(Whh1, Wih1, Wih2, wsh);
    gru1_scan<<<256, 768, 0, stream>>>(x, h1, bih1, bhh1,
                                       (const f16x8*)wsh,
                                       (const f16x8*)(wsh + 442368),
                                       wsh + 470016,
                                       sxp2, exch, h1f);
    tail_scan<<<64, 64, 0, stream>>>(sxp2, h2, h3,
                                     Whh2, bih2, bhh2, Wfc, bfc,
                                     Wih3, Whh3, bih3, bhh3,
                                     xmid, xout, h2f, h3f);
}